// Round 6
// baseline (280.119 us; speedup 1.0000x reference)
//
#include <hip/hip_runtime.h>
#include <hip/hip_cooperative_groups.h>
#include <math.h>

namespace cg = cooperative_groups;

#define NB 4
#define PP 256
#define CC 151
#define RR 51
#define CM 160                 // padded C (5 tiles of 32)
#define KI 64                  // padded per-i k slots (r in [51,64) zero in M)
#define KS 64                  // split-K: 4 i's per block
#define NROW (NB*PP)           // 1024
#define RELTOT (NB*PP*PP*RR)   // 13,369,344 floats
#define ALIM (RELTOT - 8)
#define MLB 10240              // halves per l in m-layout: 8 oct * 160 c * 8 j
#define GRID 512
#define NTHR (GRID*256)

typedef _Float16 half8 __attribute__((ext_vector_type(8)));
typedef float floatx16 __attribute__((ext_vector_type(16)));

// ws layout (bytes): m1, m2, part
#define OFF_M1 ((size_t)0)
#define OFF_M2 (OFF_M1 + (size_t)CC*MLB*2)     // +3,092,480
#define OFF_PT (OFF_M2 + (size_t)CC*MLB*2)     // part: 64*1024*160*4 = 41.9 MB

// ---------------------------------------------------------------------------
// Fused: phase1 prep M -> m1/m2 (fp16 streaming layout), phase2 GEMM
// (32x32x16 MFMA, fused transpose, split-K partials), phase3 reduce+loss.
// Cooperative launch; grid.sync() between phases.
//
// m1[l][oct][c][j] = w_r * M[l][c][oct*8+j]  (r=oct*8+j; w_0=0.5, else 0.25)
// m2[l][oct][c][j] = w_r * M[c][l][oct*8+j]  (zero r>=51 or c>=151)
// part[ks][q][c] = sum_{i in chunk,r} rel[n,i,q,r]*w_r*M[lab_i,c,r]
//                                   + rel[n,q,i,r]*w_r*M[c,lab_i,r]
// loss = mean_q( lse_c(theta) - theta[lab_q] ), theta = sum_ks part.
// ---------------------------------------------------------------------------
__global__ __launch_bounds__(256, 2)
void fused_kernel(const float* __restrict__ rel,
                  const float* __restrict__ M,
                  const int* __restrict__ labels,
                  float* __restrict__ out,
                  _Float16* __restrict__ m1,
                  _Float16* __restrict__ m2,
                  float* __restrict__ part) {
    __shared__ _Float16 Bt[2][2560];       // 10 KB; aliased as float th[] in phase 3
    const int tid = threadIdx.x;
    const unsigned gtid = blockIdx.x * 256u + tid;

    // ---------------- phase 1: prep ----------------
    if (gtid == 0) atomicExch(out, 0.f);
    for (unsigned e = gtid; e < 2u * CC * MLB; e += NTHR) {
        unsigned mat = e / (CC * MLB);
        unsigned e2  = e - mat * (CC * MLB);
        unsigned l   = e2 / MLB;
        unsigned rem = e2 - l * MLB;
        unsigned oct = rem / 1280;
        unsigned rm  = rem - oct * 1280;
        unsigned c = rm >> 3, j = rm & 7;
        unsigned r = oct * 8 + j;
        float v = 0.f;
        if (r < RR && c < CC) {
            size_t src = ((size_t)(mat ? c * CC + l : l * CC + c)) * RR + r;
            v = (r == 0 ? 0.5f : 0.25f) * M[src];
        }
        (mat ? m2 : m1)[(size_t)l * MLB + rem] = (_Float16)v;
    }

    cg::this_grid().sync();

    // ---------------- phase 2: GEMM ----------------
    {
        const int ks   = blockIdx.x & 63;
        const int rbk  = (blockIdx.x >> 6) & 1;
        const int n    = blockIdx.x >> 7;
        const int wave = tid >> 6, lane = tid & 63;
        const int m32  = lane & 31, kh = lane >> 5;
        const int i0   = ks * 4;
        const int rowimg = rbk * 128 + wave * 32 + m32;   // lane's output row q

        int labs[4];
        #pragma unroll
        for (int j = 0; j < 4; ++j) labs[j] = labels[n * PP + i0 + j];

        floatx16 acc[5];
        #pragma unroll
        for (int ct = 0; ct < 5; ++ct)
            #pragma unroll
            for (int r2 = 0; r2 < 16; ++r2) acc[ct][r2] = 0.f;

        // step h = (i_loc<<3) | (mat<<2) | t
        auto stageB = [&](int h, int buf) {
            const int il = h >> 3, mh = (h >> 2) & 1, t = h & 3;
            const _Float16* base = (mh ? m2 : m1) + (size_t)labs[il] * MLB + t * 2560;
            #pragma unroll
            for (int j = 0; j < 2; ++j) {
                int s = j * 256 + tid;           // 320 contiguous 16B chunks
                if (s < 320) {
                    __builtin_amdgcn_global_load_lds(
                        (const __attribute__((address_space(1))) unsigned int*)(base + s * 8),
                        (__attribute__((address_space(3))) unsigned int*)(&Bt[buf][(size_t)s * 8]),
                        16, 0, 0);
                }
            }
        };
        auto loadA = [&](int h, float* v) {
            const int il = h >> 3, mh = (h >> 2) & 1, t = h & 3;
            const int i = i0 + il;
            const int r0 = t * 16 + kh * 8;
            int idx = mh ? ((n * PP + rowimg) * PP + i) * RR + r0
                         : ((n * PP + i) * PP + rowimg) * RR + r0;
            idx = min(idx, ALIM);   // only reachable on i==q==255 diag (zeroed)
            const float* p = rel + idx;
            #pragma unroll
            for (int j = 0; j < 8; ++j) v[j] = p[j];
        };

        stageB(0, 0);
        float av[8];
        loadA(0, av);

        #pragma unroll 2
        for (int h = 0; h < 32; ++h) {
            __syncthreads();
            if (h < 31) stageB(h + 1, (h + 1) & 1);
            float avn[8];
            if (h < 31) loadA(h + 1, avn);

            const bool dz = (i0 + (h >> 3)) == rowimg;   // diagonal i == q
            half8 a;
            #pragma unroll
            for (int j = 0; j < 8; ++j) a[j] = (_Float16)(dz ? 0.f : av[j]);

            const _Float16* bb = &Bt[h & 1][(size_t)(kh * 160 + m32) * 8];
            #pragma unroll
            for (int ct = 0; ct < 5; ++ct) {
                half8 b = *(const half8*)(bb + ct * 256);
                acc[ct] = __builtin_amdgcn_mfma_f32_32x32x16_f16(a, b, acc[ct], 0, 0, 0);
            }
            #pragma unroll
            for (int j = 0; j < 8; ++j) av[j] = avn[j];
        }

        // C/D 32x32 layout (m74/m101): col = m32, row = (reg&3)+8*(reg>>2)+4*kh
        float* pb = part + ((size_t)ks * NROW + n * PP + rbk * 128 + wave * 32) * CM;
        #pragma unroll
        for (int ct = 0; ct < 5; ++ct)
            #pragma unroll
            for (int reg = 0; reg < 16; ++reg) {
                int row = (reg & 3) + 8 * (reg >> 2) + 4 * kh;
                pb[(size_t)row * CM + ct * 32 + m32] = acc[ct][reg];
            }
    }

    cg::this_grid().sync();

    // ---------------- phase 3: reduce + loss ----------------
    {
        float* th = (float*)Bt;       // reuse LDS
        #pragma unroll
        for (int sub = 0; sub < 2; ++sub) {
            const int row = blockIdx.x * 2 + sub;
            const int t = tid;
            if (t < CM) {
                float s = 0.f;
                #pragma unroll
                for (int ks = 0; ks < KS; ++ks)
                    s += part[((size_t)ks * NROW + row) * CM + t];
                th[t] = s;
            }
            __syncthreads();
            if (t < 64) {
                float v0 = (t < CC)       ? th[t]       : -INFINITY;
                float v1 = (t + 64 < CC)  ? th[t + 64]  : -INFINITY;
                float v2 = (t + 128 < CC) ? th[t + 128] : -INFINITY;
                float m = fmaxf(v0, fmaxf(v1, v2));
                #pragma unroll
                for (int o = 32; o > 0; o >>= 1) m = fmaxf(m, __shfl_xor(m, o, 64));
                float s = 0.f;
                if (t < CC)       s += expf(v0 - m);
                if (t + 64 < CC)  s += expf(v1 - m);
                if (t + 128 < CC) s += expf(v2 - m);
                #pragma unroll
                for (int o = 32; o > 0; o >>= 1) s += __shfl_xor(s, o, 64);
                if (t == 0)
                    atomicAdd(out, (m + logf(s) - th[labels[row]]) * (1.0f / NROW));
            }
            __syncthreads();
        }
    }
}

// ---------------------------------------------------------------------------
extern "C" void kernel_launch(void* const* d_in, const int* in_sizes, int n_in,
                              void* d_out, int out_size, void* d_ws, size_t ws_size,
                              hipStream_t stream) {
    // inputs: 0=roi_scores (unused), 1=rel_scores, 2=relationship_mat,
    //         3=roi_labels, 4=num_images (fixed B=4)
    const float* rel    = (const float*)d_in[1];
    const float* relmat = (const float*)d_in[2];
    const int*   labels = (const int*)d_in[3];
    float* out = (float*)d_out;
    char* ws = (char*)d_ws;

    _Float16* m1 = (_Float16*)(ws + OFF_M1);
    _Float16* m2 = (_Float16*)(ws + OFF_M2);
    float*  part = (float*)(ws + OFF_PT);

    void* args[] = {(void*)&rel, (void*)&relmat, (void*)&labels, (void*)&out,
                    (void*)&m1, (void*)&m2, (void*)&part};
    hipLaunchCooperativeKernel((const void*)fused_kernel, dim3(GRID), dim3(256),
                               args, 0, stream);
}

// Round 7
// 169.432 us; speedup vs baseline: 1.6533x; 1.6533x over previous
//
#include <hip/hip_runtime.h>
#include <math.h>

#define NB 4
#define PP 256
#define CC 151
#define RR 51
#define CM 160                 // padded C (5 tiles of 32)
#define KS 64                  // split-K: 4 i's per block
#define NROW (NB*PP)           // 1024
#define RELTOT (NB*PP*PP*RR)   // 13,369,344 floats
#define ALIM (RELTOT - 8)
#define MLB 10240              // halves per l per mat: 8 oct * 160 c * 8 j
#define TILE 5120              // halves per merged step (both mats, k16)

typedef _Float16 half8 __attribute__((ext_vector_type(8)));
typedef float floatx16 __attribute__((ext_vector_type(16)));

// ws layout (bytes): m1, m2, part
#define OFF_M1 ((size_t)0)
#define OFF_M2 (OFF_M1 + (size_t)CC*MLB*2)     // +3,092,480
#define OFF_PT (OFF_M2 + (size_t)CC*MLB*2)     // part: 64*1024*160*4 = 41.9 MB

// ---------------------------------------------------------------------------
// K1: streaming M layout. m1[l][oct][c][j] = w_r*M[l][c][oct*8+j],
// m2[l][oct][c][j] = w_r*M[c][l][oct*8+j]; r=oct*8+j; w_0=0.5 else 0.25;
// zero for r>=51 or c>=151. A k16 step's tile (2 octs) is 5 KB contiguous.
// ---------------------------------------------------------------------------
__global__ __launch_bounds__(256) void prep_kernel(const float* __restrict__ M,
                                                   _Float16* __restrict__ m1,
                                                   _Float16* __restrict__ m2,
                                                   float* __restrict__ out) {
    const int l = blockIdx.x;      // 0..150
    const int mat = blockIdx.y;    // 0,1
    if (l == 0 && mat == 0 && threadIdx.x == 0) *out = 0.f;
    _Float16* dst = (mat ? m2 : m1) + (size_t)l * MLB;
    for (int e = threadIdx.x; e < MLB; e += 256) {
        int oct = e / 1280;
        int rem = e - oct * 1280;
        int c = rem >> 3, j = rem & 7;
        int r = oct * 8 + j;
        float v = 0.f;
        if (r < RR && c < CC) {
            size_t src = ((size_t)(mat ? c * CC + l : l * CC + c)) * RR + r;
            v = (r == 0 ? 0.5f : 0.25f) * M[src];
        }
        dst[e] = (_Float16)v;
    }
}

// ---------------------------------------------------------------------------
// K2 (fused transpose+GEMM, 32x32x16 MFMA):
// part[ks][q][c] = sum_{i in chunk, r} rel[n,i,q,r]*w_r*M[lab_i,c,r]
//                                    + rel[n,q,i,r]*w_r*M[c,lab_i,r]
// 16 merged steps (4 i x 4 k16), each staging BOTH mats' 5 KB tiles (10 KB)
// via contiguous global_load_lds bursts; TRIPLE-buffered, stage issued 2
// steps ahead so the barrier's vmcnt(0) drain hits already-arrived loads.
// A direct fp32->reg (strided), cvt to fp16, diagonal zeroed; pad r-slots
// hit zero B columns. Grid 512 = 4 img x 2 rowblk x 64 ks; 2 blocks/CU.
// ---------------------------------------------------------------------------
__global__ __launch_bounds__(256, 2) void gemm_kernel(const float* __restrict__ rel,
                                                      const _Float16* __restrict__ m1,
                                                      const _Float16* __restrict__ m2,
                                                      const int* __restrict__ labels,
                                                      float* __restrict__ part) {
    __shared__ _Float16 Bt[3][TILE];       // 3 x 10 KB
    const int tid  = threadIdx.x;
    const int ks   = blockIdx.x & 63;
    const int rbk  = (blockIdx.x >> 6) & 1;
    const int n    = blockIdx.x >> 7;
    const int wave = tid >> 6, lane = tid & 63;
    const int m32  = lane & 31, kh = lane >> 5;
    const int i0   = ks * 4;
    const int rowimg = rbk * 128 + wave * 32 + m32;   // lane's output row q

    int labs[4];
    #pragma unroll
    for (int j = 0; j < 4; ++j) labs[j] = labels[n * PP + i0 + j];

    floatx16 acc[5];
    #pragma unroll
    for (int ct = 0; ct < 5; ++ct)
        #pragma unroll
        for (int r2 = 0; r2 < 16; ++r2) acc[ct][r2] = 0.f;

    // step h in [0,16): il = h>>2 (i), t = h&3 (k16 tile). Stage both mats:
    // chunks s<320 from m1, s in [320,640) from m2; contiguous 16B each.
    auto stageB = [&](int h, int buf) {
        const int il = h >> 2, t = h & 3;
        const size_t moff = (size_t)labs[il] * MLB + t * 2560;
        const _Float16* b1 = m1 + moff;
        const _Float16* b2 = m2 + moff;
        #pragma unroll
        for (int j = 0; j < 3; ++j) {
            int s = j * 256 + tid;
            if (s < 640) {
                const _Float16* g = (s < 320) ? b1 + (size_t)s * 8
                                              : b2 + (size_t)(s - 320) * 8;
                __builtin_amdgcn_global_load_lds(
                    (const __attribute__((address_space(1))) unsigned int*)g,
                    (__attribute__((address_space(3))) unsigned int*)(&Bt[buf][(size_t)s * 8]),
                    16, 0, 0);
            }
        }
    };
    // 16 fp32 A elements: [0..8) mat0 = rel[n,i,q,*], [8..16) mat1 = rel[n,q,i,*]
    auto loadA = [&](int h, float* v) {
        const int il = h >> 2, t = h & 3;
        const int i = i0 + il;
        const int r0 = t * 16 + kh * 8;
        int idx0 = ((n * PP + i) * PP + rowimg) * RR + r0;
        int idx1 = ((n * PP + rowimg) * PP + i) * RR + r0;
        idx0 = min(idx0, ALIM);    // clamp reachable only on i==q==255 diag (zeroed)
        idx1 = min(idx1, ALIM);
        const float* p0 = rel + idx0;
        const float* p1 = rel + idx1;
        #pragma unroll
        for (int j = 0; j < 8; ++j) { v[j] = p0[j]; v[8 + j] = p1[j]; }
    };

    stageB(0, 0);
    stageB(1, 1);
    float av[16];
    loadA(0, av);

    for (int h = 0; h < 16; ++h) {
        __syncthreads();                    // Bt[h%3] resident (staged >=1 step ago)
        if (h < 14) stageB(h + 2, (h + 2) % 3);
        float avn[16];
        if (h < 15) loadA(h + 1, avn);

        const bool dz = (i0 + (h >> 2)) == rowimg;   // diagonal i == q
        half8 a0, a1;
        #pragma unroll
        for (int j = 0; j < 8; ++j) {
            a0[j] = (_Float16)(dz ? 0.f : av[j]);
            a1[j] = (_Float16)(dz ? 0.f : av[8 + j]);
        }

        const _Float16* bb = &Bt[h % 3][(size_t)(kh * 160 + m32) * 8];
        #pragma unroll
        for (int ct = 0; ct < 5; ++ct) {
            half8 b0 = *(const half8*)(bb + ct * 256);
            half8 b1 = *(const half8*)(bb + 2560 + ct * 256);
            acc[ct] = __builtin_amdgcn_mfma_f32_32x32x16_f16(a0, b0, acc[ct], 0, 0, 0);
            acc[ct] = __builtin_amdgcn_mfma_f32_32x32x16_f16(a1, b1, acc[ct], 0, 0, 0);
        }
        #pragma unroll
        for (int j = 0; j < 16; ++j) av[j] = avn[j];
    }

    // C/D 32x32 layout (m74/m101): col = m32, row = (reg&3)+8*(reg>>2)+4*kh
    float* pb = part + ((size_t)ks * NROW + n * PP + rbk * 128 + wave * 32) * CM;
    #pragma unroll
    for (int ct = 0; ct < 5; ++ct)
        #pragma unroll
        for (int reg = 0; reg < 16; ++reg) {
            int row = (reg & 3) + 8 * (reg >> 2) + 4 * kh;
            pb[(size_t)row * CM + ct * 32 + m32] = acc[ct][reg];
        }
}

// ---------------------------------------------------------------------------
// K3: theta[row][c] = sum_ks part; loss = lse(theta) - theta[lab]; mean.
// ---------------------------------------------------------------------------
__global__ __launch_bounds__(256) void reduce_loss_kernel(const float* __restrict__ part,
                                                          const int* __restrict__ labels,
                                                          float* __restrict__ out) {
    __shared__ float th[CM];
    const int row = blockIdx.x;
    const int t = threadIdx.x;
    if (t < CM) {
        float s = 0.f;
        #pragma unroll
        for (int ks = 0; ks < KS; ++ks)
            s += part[((size_t)ks * NROW + row) * CM + t];
        th[t] = s;
    }
    __syncthreads();
    if (t < 64) {
        float v0 = (t < CC)       ? th[t]       : -INFINITY;
        float v1 = (t + 64 < CC)  ? th[t + 64]  : -INFINITY;
        float v2 = (t + 128 < CC) ? th[t + 128] : -INFINITY;
        float m = fmaxf(v0, fmaxf(v1, v2));
        #pragma unroll
        for (int o = 32; o > 0; o >>= 1) m = fmaxf(m, __shfl_xor(m, o, 64));
        float s = 0.f;
        if (t < CC)       s += expf(v0 - m);
        if (t + 64 < CC)  s += expf(v1 - m);
        if (t + 128 < CC) s += expf(v2 - m);
        #pragma unroll
        for (int o = 32; o > 0; o >>= 1) s += __shfl_xor(s, o, 64);
        if (t == 0) {
            atomicAdd(out, (m + logf(s) - th[labels[row]]) * (1.0f / NROW));
        }
    }
}

// ---------------------------------------------------------------------------
extern "C" void kernel_launch(void* const* d_in, const int* in_sizes, int n_in,
                              void* d_out, int out_size, void* d_ws, size_t ws_size,
                              hipStream_t stream) {
    // inputs: 0=roi_scores (unused), 1=rel_scores, 2=relationship_mat,
    //         3=roi_labels, 4=num_images (fixed B=4)
    const float* rel    = (const float*)d_in[1];
    const float* relmat = (const float*)d_in[2];
    const int*   labels = (const int*)d_in[3];
    float* out = (float*)d_out;
    char* ws = (char*)d_ws;

    _Float16* m1 = (_Float16*)(ws + OFF_M1);
    _Float16* m2 = (_Float16*)(ws + OFF_M2);
    float*  part = (float*)(ws + OFF_PT);

    prep_kernel<<<dim3(CC, 2), 256, 0, stream>>>(relmat, m1, m2, out);
    gemm_kernel<<<NB * 2 * KS, 256, 0, stream>>>(rel, m1, m2, labels, part);
    reduce_loss_kernel<<<NROW, 256, 0, stream>>>(part, labels, out);
}